// Round 6
// baseline (247.561 us; speedup 1.0000x reference)
//
#include <hip/hip_runtime.h>
#include <hip/hip_bf16.h>
#include <math.h>

#define LTOK 4096
#define EDIM 512
#define SDIM 1024
#define HDIM 150
#define PPAD 152           // padded row stride for P1/P2/PE (fp32)
#define MAXN 10
#define TOTAL_ROWS 40915   // sum_{n=1..10} (L - n + 1)
#define KA 1536            // padded K for token GEMM: 1024 states + 512 embeds
#define NC 640             // padded col count (600 real: P1|P2|AH1|PE)
#define K2 160             // padded K and N for 150x150 layers

typedef __attribute__((ext_vector_type(8))) short bfrag;   // 8 bf16 in 4 VGPRs
typedef __attribute__((ext_vector_type(4))) float ffrag;   // MFMA C/D

__device__ inline ushort f2bf(float f) {
    __hip_bfloat16 h = __float2bfloat16(f);
    return *(ushort*)&h;
}
__device__ inline float bf2f(ushort u) {
    __hip_bfloat16 h = *(__hip_bfloat16*)&u;
    return __bfloat162float(h);
}

#define ITEMS_A   (LTOK * (KA / 8))   // 786432  Ab
#define ITEMS_W   (NC * (KA / 8))     // 122880  Wh/Wl
#define ITEMS_W2  (K2 * (K2 / 8))     // 3200    W2h/W2l (sW2)
#define ITEMS_A2  (K2 * (K2 / 8))     // 3200    A2h/A2l (aW2)
#define ITEMS_Z   (LTOK * K2 / 8)     // 81920   zero AH1b (incl. k-pad)
#define ITEMS_TOT (ITEMS_A + ITEMS_W + ITEMS_W2 + ITEMS_A2 + ITEMS_Z)

// ---------------------------------------------------------------------------
// prep: bf16 conversions + transposes + hi/lo splits + AH1b zero-init.
// ---------------------------------------------------------------------------
__global__ __launch_bounds__(256) void prep_kernel(
    const float* __restrict__ embeds, const float* __restrict__ states,
    const float* __restrict__ aW1, const float* __restrict__ aW2,
    const float* __restrict__ sW1, const float* __restrict__ sW2,
    ushort* __restrict__ Ab, ushort* __restrict__ Wh, ushort* __restrict__ Wl,
    ushort* __restrict__ W2h, ushort* __restrict__ W2l,
    ushort* __restrict__ A2h, ushort* __restrict__ A2l,
    ushort* __restrict__ AH1b)
{
    int it = blockIdx.x * 256 + threadIdx.x;
    if (it < ITEMS_A) {
        const int r = it / (KA / 8), kc = it % (KA / 8);
        const int k0 = kc * 8;
        const float* src = (k0 < SDIM) ? (states + (size_t)r * SDIM + k0)
                                       : (embeds + (size_t)r * EDIM + (k0 - SDIM));
        const float4 v0 = *(const float4*)src;
        const float4 v1 = *(const float4*)(src + 4);
        ushort o[8] = {f2bf(v0.x), f2bf(v0.y), f2bf(v0.z), f2bf(v0.w),
                       f2bf(v1.x), f2bf(v1.y), f2bf(v1.z), f2bf(v1.w)};
        *(uint4*)(Ab + (size_t)r * KA + k0) = *(uint4*)o;
        return;
    }
    it -= ITEMS_A;
    if (it < ITEMS_W) {
        const int c = it / (KA / 8), kc = it % (KA / 8);
        const int k0 = kc * 8;
        const int g = (c < 600) ? (c / HDIM) : -1;
        const int cj = c % HDIM;
        ushort oh[8], ol[8];
        for (int j = 0; j < 8; ++j) {
            const int k = k0 + j;
            float wv = 0.f;
            if (g == 0 && k < SDIM) wv = sW1[(size_t)k * HDIM + cj];
            else if (g == 1 && k < SDIM) wv = sW1[(size_t)(SDIM + k) * HDIM + cj];
            else if (g == 2 && k < SDIM) wv = aW1[(size_t)k * HDIM + cj];
            else if (g == 3 && k >= SDIM) wv = sW1[(size_t)(SDIM + k) * HDIM + cj]; // rows 2048+(k-1024)
            const ushort hb = f2bf(wv);
            oh[j] = hb;
            ol[j] = f2bf(wv - bf2f(hb));
        }
        *(uint4*)(Wh + (size_t)c * KA + k0) = *(uint4*)oh;
        *(uint4*)(Wl + (size_t)c * KA + k0) = *(uint4*)ol;
        return;
    }
    it -= ITEMS_W;
    if (it < ITEMS_W2 + ITEMS_A2) {
        const bool is_a = (it >= ITEMS_W2);
        const int li = is_a ? (it - ITEMS_W2) : it;
        const float* src = is_a ? aW2 : sW2;
        ushort* dh = is_a ? A2h : W2h;
        ushort* dl = is_a ? A2l : W2l;
        const int c = li / (K2 / 8), kc = li % (K2 / 8);
        const int k0 = kc * 8;
        ushort oh[8], ol[8];
        for (int j = 0; j < 8; ++j) {
            const int k = k0 + j;
            float wv = (c < HDIM && k < HDIM) ? src[(size_t)k * HDIM + c] : 0.f;
            const ushort hb = f2bf(wv);
            oh[j] = hb;
            ol[j] = f2bf(wv - bf2f(hb));
        }
        *(uint4*)(dh + (size_t)c * K2 + k0) = *(uint4*)oh;
        *(uint4*)(dl + (size_t)c * K2 + k0) = *(uint4*)ol;
        return;
    }
    it -= ITEMS_W2 + ITEMS_A2;
    if (it < ITEMS_Z) {
        const uint4 z = {0u, 0u, 0u, 0u};
        *(uint4*)(AH1b + (size_t)it * 8) = z;
    }
}

// ---------------------------------------------------------------------------
// k_proj v3: C[4096 x 640] via mfma_f32_16x16x32_bf16 — NO LDS, NO barriers.
// A-fragments are direct b128 loads from row-major Ab (contiguous k per lane),
// B hi/lo streamed from L2. BM=64 x BN=64, grid 640, 4 waves (2x2), wave-tile
// 32x32. All loads affine & independent -> deep compiler pipelining.
// ---------------------------------------------------------------------------
#define BM 64
#define BN 64
__global__ __launch_bounds__(256) void k_proj(
    const ushort* __restrict__ Ab, const ushort* __restrict__ Wh,
    const ushort* __restrict__ Wl, const float* __restrict__ ab1,
    float* __restrict__ P1, float* __restrict__ P2,
    float* __restrict__ PE, ushort* __restrict__ AH1b)
{
    const int bM = blockIdx.x & 63, bN = blockIdx.x >> 6;
    const int tid = threadIdx.x;
    const int w = tid >> 6, lane = tid & 63;
    const int quad = lane >> 4, l16 = lane & 15;
    const int wm = w & 1, wn = w >> 1;

    ffrag acc[2][2];
#pragma unroll
    for (int t = 0; t < 2; ++t)
#pragma unroll
        for (int u = 0; u < 2; ++u) acc[t][u] = (ffrag){0.f, 0.f, 0.f, 0.f};

    const int rowg0 = bM * BM;
    const int colb = bN * BN + wn * 32;

    // per-lane streaming pointers (advance by 32 bf16 per k-iter)
    const ushort* ap0 = Ab + (size_t)(rowg0 + wm * 32 + l16) * KA + quad * 8;
    const ushort* ap1 = ap0 + (size_t)16 * KA;
    const ushort* bh0 = Wh + (size_t)(colb + l16) * KA + quad * 8;
    const ushort* bl0 = Wl + (size_t)(colb + l16) * KA + quad * 8;
    const ushort* bh1 = bh0 + (size_t)16 * KA;
    const ushort* bl1 = bl0 + (size_t)16 * KA;

#pragma unroll 2
    for (int kt = 0; kt < KA / 32; ++kt) {
        const int k0 = kt * 32;
        const bfrag a0 = *(const bfrag*)(ap0 + k0);
        const bfrag a1 = *(const bfrag*)(ap1 + k0);
        const bfrag b0h = *(const bfrag*)(bh0 + k0);
        const bfrag b0l = *(const bfrag*)(bl0 + k0);
        const bfrag b1h = *(const bfrag*)(bh1 + k0);
        const bfrag b1l = *(const bfrag*)(bl1 + k0);
        acc[0][0] = __builtin_amdgcn_mfma_f32_16x16x32_bf16(a0, b0h, acc[0][0], 0, 0, 0);
        acc[0][0] = __builtin_amdgcn_mfma_f32_16x16x32_bf16(a0, b0l, acc[0][0], 0, 0, 0);
        acc[1][0] = __builtin_amdgcn_mfma_f32_16x16x32_bf16(a1, b0h, acc[1][0], 0, 0, 0);
        acc[1][0] = __builtin_amdgcn_mfma_f32_16x16x32_bf16(a1, b0l, acc[1][0], 0, 0, 0);
        acc[0][1] = __builtin_amdgcn_mfma_f32_16x16x32_bf16(a0, b1h, acc[0][1], 0, 0, 0);
        acc[0][1] = __builtin_amdgcn_mfma_f32_16x16x32_bf16(a0, b1l, acc[0][1], 0, 0, 0);
        acc[1][1] = __builtin_amdgcn_mfma_f32_16x16x32_bf16(a1, b1h, acc[1][1], 0, 0, 0);
        acc[1][1] = __builtin_amdgcn_mfma_f32_16x16x32_bf16(a1, b1l, acc[1][1], 0, 0, 0);
    }

#pragma unroll
    for (int t = 0; t < 2; ++t)
#pragma unroll
        for (int u = 0; u < 2; ++u) {
            const int col = colb + u * 16 + l16;
#pragma unroll
            for (int r = 0; r < 4; ++r) {
                const int row = rowg0 + wm * 32 + t * 16 + quad * 4 + r;
                const float v = acc[t][u][r];
                if (col < 150)      P1[(size_t)row * PPAD + col] = v;
                else if (col < 300) P2[(size_t)row * PPAD + (col - 150)] = v;
                else if (col < 450) AH1b[(size_t)row * K2 + (col - 300)] =
                                        f2bf(fmaxf(v + ab1[col - 300], 0.f));
                else if (col < 600) PE[(size_t)row * PPAD + (col - 450)] = v;
            }
        }
}

// ---------------------------------------------------------------------------
// attn_tail v3 (MFMA): one wave per block, 16 tokens, grid 256.
// ---------------------------------------------------------------------------
__global__ __launch_bounds__(64) void attn_tail(
    const ushort* __restrict__ AH1b, const ushort* __restrict__ A2h,
    const ushort* __restrict__ A2l, const float* __restrict__ ab2,
    const float* __restrict__ aW3, const float* __restrict__ ab3,
    float* __restrict__ attns)
{
    const int tok0 = blockIdx.x * 16;
    const int lane = threadIdx.x;
    const int quad = lane >> 4, l16 = lane & 15;

    bfrag af[5];
#pragma unroll
    for (int ks = 0; ks < 5; ++ks)
        af[ks] = *(const bfrag*)(AH1b + (size_t)(tok0 + l16) * K2 + ks * 32 + quad * 8);

    float part[4] = {0.f, 0.f, 0.f, 0.f};
    for (int ct = 0; ct < 10; ++ct) {
        ffrag acc = (ffrag){0.f, 0.f, 0.f, 0.f};
        const int col = ct * 16 + l16;
        const ushort* bh = A2h + (size_t)col * K2;
        const ushort* bl = A2l + (size_t)col * K2;
#pragma unroll
        for (int ks = 0; ks < 5; ++ks) {
            const bfrag fh = *(const bfrag*)(bh + ks * 32 + quad * 8);
            const bfrag fl = *(const bfrag*)(bl + ks * 32 + quad * 8);
            acc = __builtin_amdgcn_mfma_f32_16x16x32_bf16(af[ks], fh, acc, 0, 0, 0);
            acc = __builtin_amdgcn_mfma_f32_16x16x32_bf16(af[ks], fl, acc, 0, 0, 0);
        }
        const float s2 = (col < HDIM) ? ab2[col] : 0.f;
        const float s3 = (col < HDIM) ? aW3[col] : 0.f;
#pragma unroll
        for (int r = 0; r < 4; ++r) part[r] += fmaxf(acc[r] + s2, 0.f) * s3;
    }

#pragma unroll
    for (int off = 1; off < 16; off <<= 1) {
#pragma unroll
        for (int r = 0; r < 4; ++r) part[r] += __shfl_xor(part[r], off, 64);
    }
    if (l16 == 0) {
        const float b3 = ab3[0];
#pragma unroll
        for (int r = 0; r < 4; ++r)
            attns[tok0 + quad * 4 + r] = part[r] + b3;
    }
}

// ---------------------------------------------------------------------------
// span v2: uniform-n blocks. blockIdx = nIdx*64 + mChunk; n = nIdx+1,
// rows m in [mChunk*64, min(+64, L-n+1)). Output at offset_n + m.
// Phase 1: fully-unrolled predicated 10-deep PE prefetch (no dependent-load
// chain). Phase 2: MFMA layer-2 as before.
// ---------------------------------------------------------------------------
#define RB2 64
__global__ __launch_bounds__(256) void span_kernel(
    const float* __restrict__ attns, const float* __restrict__ P1,
    const float* __restrict__ P2, const float* __restrict__ PE,
    const float* __restrict__ sb1, const ushort* __restrict__ W2h,
    const ushort* __restrict__ W2l, const float* __restrict__ sb2,
    const float* __restrict__ sW3, const float* __restrict__ sb3,
    float* __restrict__ out)
{
    const int nIdx = blockIdx.x >> 6, mChunk = blockIdx.x & 63;
    const int n = nIdx + 1;
    const int Mn = LTOK - n + 1;
    const int m0 = mChunk * 64;
    const int nrows = min(64, Mn - m0);
    const int offn = nIdx * LTOK - (nIdx * (nIdx - 1)) / 2;  // sum_{j<n}(L-j+1)

    const int tid = threadIdx.x;
    const int w = tid >> 6, lane = tid & 63, quad = lane >> 4, l16 = lane & 15;

    __shared__ __align__(16) ushort h1b[RB2 * K2];
    __shared__ float wgt[RB2][MAXN];

    if (tid < RB2) {
        const int m = min(m0 + tid, Mn - 1);
        float mx = -1e30f;
        for (int j = 0; j < n; ++j) mx = fmaxf(mx, attns[m + j]);
        float tp[MAXN]; float s = 0.f;
        for (int j = 0; j < n; ++j) { tp[j] = expf(attns[m + j] - mx); s += tp[j]; }
        const float inv = 1.f / s;
#pragma unroll
        for (int j = 0; j < MAXN; ++j) wgt[tid][j] = (j < n) ? tp[j] * inv : 0.f;
    }
    __syncthreads();

    // phase 1: h1 fp32 (float4) -> bf16 LDS; 10 independent PE loads per item
    for (int item = tid; item < RB2 * (K2 / 4); item += 256) {
        const int r = item / (K2 / 4), cq = item % (K2 / 4);
        const int c0 = cq * 4;
        const int m = min(m0 + r, Mn - 1);
        float4 a = {0.f, 0.f, 0.f, 0.f};
        if (c0 < HDIM) {
            const float4 p1 = *(const float4*)(P1 + (size_t)m * PPAD + c0);
            const float4 p2 = *(const float4*)(P2 + (size_t)(m + n - 1) * PPAD + c0);
            a.x = p1.x + p2.x; a.y = p1.y + p2.y;
            a.z = p1.z + p2.z; a.w = p1.w + p2.w;
#pragma unroll
            for (int j = 0; j < MAXN; ++j) {
                const int mj = min(m + j, LTOK - 1);        // clamped; wj=0 past n
                const float4 pe = *(const float4*)(PE + (size_t)mj * PPAD + c0);
                const float wj = wgt[r][j];
                a.x = fmaf(wj, pe.x, a.x); a.y = fmaf(wj, pe.y, a.y);
                a.z = fmaf(wj, pe.z, a.z); a.w = fmaf(wj, pe.w, a.w);
            }
        }
        ushort o[4];
        o[0] = (c0 + 0 < HDIM) ? f2bf(fmaxf(a.x + sb1[c0 + 0], 0.f)) : (ushort)0;
        o[1] = (c0 + 1 < HDIM) ? f2bf(fmaxf(a.y + sb1[c0 + 1], 0.f)) : (ushort)0;
        o[2] = (c0 + 2 < HDIM) ? f2bf(fmaxf(a.z + sb1[c0 + 2], 0.f)) : (ushort)0;
        o[3] = (c0 + 3 < HDIM) ? f2bf(fmaxf(a.w + sb1[c0 + 3], 0.f)) : (ushort)0;
        *(uint2*)&h1b[r * K2 + c0] = *(uint2*)o;
    }
    __syncthreads();

    // phase 2: wave w -> rows w*16..+15, all 10 col-tiles
    bfrag af[5];
#pragma unroll
    for (int ks = 0; ks < 5; ++ks)
        af[ks] = *(const bfrag*)&h1b[(w * 16 + l16) * K2 + ks * 32 + quad * 8];

    float part[4] = {0.f, 0.f, 0.f, 0.f};
    for (int ct = 0; ct < 10; ++ct) {
        ffrag acc = (ffrag){0.f, 0.f, 0.f, 0.f};
        const int col = ct * 16 + l16;
        const ushort* bh = W2h + (size_t)col * K2;
        const ushort* bl = W2l + (size_t)col * K2;
#pragma unroll
        for (int ks = 0; ks < 5; ++ks) {
            const bfrag fh = *(const bfrag*)(bh + ks * 32 + quad * 8);
            const bfrag fl = *(const bfrag*)(bl + ks * 32 + quad * 8);
            acc = __builtin_amdgcn_mfma_f32_16x16x32_bf16(af[ks], fh, acc, 0, 0, 0);
            acc = __builtin_amdgcn_mfma_f32_16x16x32_bf16(af[ks], fl, acc, 0, 0, 0);
        }
        const float s2 = (col < HDIM) ? sb2[col] : 0.f;
        const float s3 = (col < HDIM) ? sW3[col] : 0.f;
#pragma unroll
        for (int r = 0; r < 4; ++r) part[r] += fmaxf(acc[r] + s2, 0.f) * s3;
    }

#pragma unroll
    for (int off = 1; off < 16; off <<= 1) {
#pragma unroll
        for (int r = 0; r < 4; ++r) part[r] += __shfl_xor(part[r], off, 64);
    }
    if (l16 == 0) {
        const float b3 = sb3[0];
#pragma unroll
        for (int r = 0; r < 4; ++r) {
            const int lr = w * 16 + quad * 4 + r;
            if (lr < nrows) out[offn + m0 + lr] = part[r] + b3;
        }
    }
}

// ---------------------------------------------------------------------------
extern "C" void kernel_launch(void* const* d_in, const int* in_sizes, int n_in,
                              void* d_out, int out_size, void* d_ws, size_t ws_size,
                              hipStream_t stream) {
    const float* embeds = (const float*)d_in[0];
    const float* states = (const float*)d_in[1];
    const float* aW1 = (const float*)d_in[2];
    const float* ab1 = (const float*)d_in[3];
    const float* aW2 = (const float*)d_in[4];
    const float* ab2 = (const float*)d_in[5];
    const float* aW3 = (const float*)d_in[6];
    const float* ab3 = (const float*)d_in[7];
    const float* sW1 = (const float*)d_in[8];
    const float* sb1 = (const float*)d_in[9];
    const float* sW2 = (const float*)d_in[10];
    const float* sb2 = (const float*)d_in[11];
    const float* sW3 = (const float*)d_in[12];
    const float* sb3 = (const float*)d_in[13];
    float* out = (float*)d_out;

    // ws: fp32 attns | P1 | P2 | PE (PPAD rows), bf16 AH1b | Ab | Wh | Wl |
    //     W2h | W2l | A2h | A2l   (~25.5 MB)
    float* attns = (float*)d_ws;
    float* P1 = attns + LTOK;
    float* P2 = P1 + (size_t)LTOK * PPAD;
    float* PE = P2 + (size_t)LTOK * PPAD;
    ushort* AH1b = (ushort*)(PE + (size_t)LTOK * PPAD);  // LTOK*K2
    ushort* Ab  = AH1b + (size_t)LTOK * K2;              // LTOK*KA
    ushort* Wh  = Ab + (size_t)LTOK * KA;                // NC*KA
    ushort* Wl  = Wh + (size_t)NC * KA;
    ushort* W2h = Wl + (size_t)NC * KA;                  // K2*K2 each
    ushort* W2l = W2h + (size_t)K2 * K2;
    ushort* A2h = W2l + (size_t)K2 * K2;
    ushort* A2l = A2h + (size_t)K2 * K2;

    prep_kernel<<<(ITEMS_TOT + 255) / 256, 256, 0, stream>>>(
        embeds, states, aW1, aW2, sW1, sW2,
        Ab, Wh, Wl, W2h, W2l, A2h, A2l, AH1b);
    k_proj<<<(LTOK / BM) * (NC / BN), 256, 0, stream>>>(
        Ab, Wh, Wl, ab1, P1, P2, PE, AH1b);
    attn_tail<<<LTOK / 16, 64, 0, stream>>>(
        AH1b, A2h, A2l, ab2, aW3, ab3, attns);
    span_kernel<<<640, 256, 0, stream>>>(
        attns, P1, P2, PE, sb1, W2h, W2l, sb2, sW3, sb3, out);
}

// Round 7
// 175.256 us; speedup vs baseline: 1.4126x; 1.4126x over previous
//
#include <hip/hip_runtime.h>
#include <hip/hip_bf16.h>
#include <math.h>

#define LTOK 4096
#define EDIM 512
#define SDIM 1024
#define HDIM 150
#define PPAD 152           // padded row stride for P1/P2/PE (fp32)
#define MAXN 10
#define TOTAL_ROWS 40915   // sum_{n=1..10} (L - n + 1)
#define KA 1536            // padded K for token GEMM: 1024 states + 512 embeds
#define NC 640             // padded col count (600 real: P1|P2|AH1|PE)
#define K2 160             // padded K and N for 150x150 layers
#define NKT (KA / 32)      // 48 k-tiles

typedef __attribute__((ext_vector_type(8))) short bfrag;   // 8 bf16 in 4 VGPRs
typedef __attribute__((ext_vector_type(4))) float ffrag;   // MFMA C/D

__device__ inline ushort f2bf(float f) {
    __hip_bfloat16 h = __float2bfloat16(f);
    return *(ushort*)&h;
}
__device__ inline float bf2f(ushort u) {
    __hip_bfloat16 h = *(__hip_bfloat16*)&u;
    return __bfloat162float(h);
}

// Packed-fragment layouts: a wave's frag load = base + lane*8 elems (16 B/lane,
// 1 KB contiguous per wave — ideal coalescing; no 16-line gathers).
//   Apk [(g*48 + kt)*64 + lane][8]      : A[row=g*16+l16][k=kt*32+quad*8+j]
//   Wpk [((cg*48 + kt)*2 + h)*64 + lane][8] : W[col=cg*16+l16][k...], h=hi/lo
//   W2pk/A2pk [((ct*5+ks)*2+h)*64 + lane][8]

#define ITEMS_A   (LTOK * (KA / 8))   // 786432  Apk (g=256, kt=48, lane=64)
#define ITEMS_W   (NC * (KA / 8))     // 122880  Wpk (cg=40, kt=48, lane=64)
#define ITEMS_W2  (K2 * (K2 / 8))     // 3200    W2pk (tk=50, lane=64)
#define ITEMS_A2  (K2 * (K2 / 8))     // 3200    A2pk
#define ITEMS_Z   (LTOK * K2 / 8)     // 81920   zero AH1b (incl. k-pad)
#define ITEMS_TOT (ITEMS_A + ITEMS_W + ITEMS_W2 + ITEMS_A2 + ITEMS_Z)

// ---------------------------------------------------------------------------
// prep: bf16 conversion + MFMA-fragment packing + hi/lo splits + AH1b zero.
// ---------------------------------------------------------------------------
__global__ __launch_bounds__(256) void prep_kernel(
    const float* __restrict__ embeds, const float* __restrict__ states,
    const float* __restrict__ aW1, const float* __restrict__ aW2,
    const float* __restrict__ sW1, const float* __restrict__ sW2,
    ushort* __restrict__ Apk, ushort* __restrict__ Wpk,
    ushort* __restrict__ W2pk, ushort* __restrict__ A2pk,
    ushort* __restrict__ AH1b)
{
    int it = blockIdx.x * 256 + threadIdx.x;
    if (it < ITEMS_A) {
        const int rem = it % 3072;               // 48*64
        const int g = it / 3072, kt = rem >> 6, lane = rem & 63;
        const int row = g * 16 + (lane & 15);
        const int k0 = kt * 32 + (lane >> 4) * 8;
        const float* src = (k0 < SDIM) ? (states + (size_t)row * SDIM + k0)
                                       : (embeds + (size_t)row * EDIM + (k0 - SDIM));
        const float4 v0 = *(const float4*)src;
        const float4 v1 = *(const float4*)(src + 4);
        ushort o[8] = {f2bf(v0.x), f2bf(v0.y), f2bf(v0.z), f2bf(v0.w),
                       f2bf(v1.x), f2bf(v1.y), f2bf(v1.z), f2bf(v1.w)};
        *(uint4*)(Apk + (size_t)it * 8) = *(uint4*)o;
        return;
    }
    it -= ITEMS_A;
    if (it < ITEMS_W) {
        const int rem = it % 3072;
        const int cg = it / 3072, kt = rem >> 6, lane = rem & 63;
        const int col = cg * 16 + (lane & 15);
        const int k0 = kt * 32 + (lane >> 4) * 8;
        const int g4 = (col < 600) ? (col / HDIM) : -1;
        const int cj = col % HDIM;
        ushort oh[8], ol[8];
        for (int j = 0; j < 8; ++j) {
            const int k = k0 + j;
            float wv = 0.f;
            if (g4 == 0 && k < SDIM) wv = sW1[(size_t)k * HDIM + cj];
            else if (g4 == 1 && k < SDIM) wv = sW1[(size_t)(SDIM + k) * HDIM + cj];
            else if (g4 == 2 && k < SDIM) wv = aW1[(size_t)k * HDIM + cj];
            else if (g4 == 3 && k >= SDIM) wv = sW1[(size_t)(SDIM + k) * HDIM + cj]; // rows 2048+(k-1024)
            const ushort hb = f2bf(wv);
            oh[j] = hb;
            ol[j] = f2bf(wv - bf2f(hb));
        }
        const size_t tk = (size_t)cg * 48 + kt;
        *(uint4*)(Wpk + ((tk * 2 + 0) * 64 + lane) * 8) = *(uint4*)oh;
        *(uint4*)(Wpk + ((tk * 2 + 1) * 64 + lane) * 8) = *(uint4*)ol;
        return;
    }
    it -= ITEMS_W;
    if (it < ITEMS_W2 + ITEMS_A2) {
        const bool is_a = (it >= ITEMS_W2);
        const int li = is_a ? (it - ITEMS_W2) : it;
        const float* src = is_a ? aW2 : sW2;
        ushort* dst = is_a ? A2pk : W2pk;
        const int tk = li >> 6, lane = li & 63;          // tk = ct*5+ks (0..49)
        const int col = (tk / 5) * 16 + (lane & 15);
        const int k0 = (tk % 5) * 32 + (lane >> 4) * 8;
        ushort oh[8], ol[8];
        for (int j = 0; j < 8; ++j) {
            const int k = k0 + j;
            float wv = (col < HDIM && k < HDIM) ? src[(size_t)k * HDIM + col] : 0.f;
            const ushort hb = f2bf(wv);
            oh[j] = hb;
            ol[j] = f2bf(wv - bf2f(hb));
        }
        *(uint4*)(dst + ((size_t)(tk * 2 + 0) * 64 + lane) * 8) = *(uint4*)oh;
        *(uint4*)(dst + ((size_t)(tk * 2 + 1) * 64 + lane) * 8) = *(uint4*)ol;
        return;
    }
    it -= ITEMS_W2 + ITEMS_A2;
    if (it < ITEMS_Z) {
        const uint4 z = {0u, 0u, 0u, 0u};
        *(uint4*)(AH1b + (size_t)it * 8) = z;
    }
}

// ---------------------------------------------------------------------------
// k_proj v4: C[4096 x 640] via mfma_f32_16x16x32_bf16 — no LDS, no barriers,
// ALL loads contiguous packed-fragment streams. BM=64 x BN=64, grid 640,
// 4 waves (2x2), wave-tile 32x32. 2 A-frags + 4 B-frags + 8 MFMAs per kt.
// ---------------------------------------------------------------------------
__global__ __launch_bounds__(256) void k_proj(
    const ushort* __restrict__ Apk, const ushort* __restrict__ Wpk,
    const float* __restrict__ ab1,
    float* __restrict__ P1, float* __restrict__ P2,
    float* __restrict__ PE, ushort* __restrict__ AH1b)
{
    const int bM = blockIdx.x & 63, bN = blockIdx.x >> 6;
    const int tid = threadIdx.x;
    const int w = tid >> 6, lane = tid & 63;
    const int quad = lane >> 4, l16 = lane & 15;
    const int wm = w & 1, wn = w >> 1;

    const int gbase = bM * 4 + wm * 2;      // two 16-row groups
    const int cgbase = bN * 4 + wn * 2;     // two 16-col groups

    ffrag acc[2][2];
#pragma unroll
    for (int t = 0; t < 2; ++t)
#pragma unroll
        for (int u = 0; u < 2; ++u) acc[t][u] = (ffrag){0.f, 0.f, 0.f, 0.f};

    const ushort* a0p = Apk + ((size_t)(gbase + 0) * NKT) * 512 + lane * 8;
    const ushort* a1p = Apk + ((size_t)(gbase + 1) * NKT) * 512 + lane * 8;
    const ushort* b0p = Wpk + ((size_t)(cgbase + 0) * NKT * 2) * 512 + lane * 8;
    const ushort* b1p = Wpk + ((size_t)(cgbase + 1) * NKT * 2) * 512 + lane * 8;

#pragma unroll 2
    for (int kt = 0; kt < NKT; ++kt) {
        const bfrag a0  = *(const bfrag*)(a0p + (size_t)kt * 512);
        const bfrag a1  = *(const bfrag*)(a1p + (size_t)kt * 512);
        const bfrag b0h = *(const bfrag*)(b0p + (size_t)kt * 1024);
        const bfrag b0l = *(const bfrag*)(b0p + (size_t)kt * 1024 + 512);
        const bfrag b1h = *(const bfrag*)(b1p + (size_t)kt * 1024);
        const bfrag b1l = *(const bfrag*)(b1p + (size_t)kt * 1024 + 512);
        acc[0][0] = __builtin_amdgcn_mfma_f32_16x16x32_bf16(a0, b0h, acc[0][0], 0, 0, 0);
        acc[0][0] = __builtin_amdgcn_mfma_f32_16x16x32_bf16(a0, b0l, acc[0][0], 0, 0, 0);
        acc[1][0] = __builtin_amdgcn_mfma_f32_16x16x32_bf16(a1, b0h, acc[1][0], 0, 0, 0);
        acc[1][0] = __builtin_amdgcn_mfma_f32_16x16x32_bf16(a1, b0l, acc[1][0], 0, 0, 0);
        acc[0][1] = __builtin_amdgcn_mfma_f32_16x16x32_bf16(a0, b1h, acc[0][1], 0, 0, 0);
        acc[0][1] = __builtin_amdgcn_mfma_f32_16x16x32_bf16(a0, b1l, acc[0][1], 0, 0, 0);
        acc[1][1] = __builtin_amdgcn_mfma_f32_16x16x32_bf16(a1, b1h, acc[1][1], 0, 0, 0);
        acc[1][1] = __builtin_amdgcn_mfma_f32_16x16x32_bf16(a1, b1l, acc[1][1], 0, 0, 0);
    }

#pragma unroll
    for (int t = 0; t < 2; ++t)
#pragma unroll
        for (int u = 0; u < 2; ++u) {
            const int col = (cgbase + u) * 16 + l16;
#pragma unroll
            for (int r = 0; r < 4; ++r) {
                const int row = (gbase + t) * 16 + quad * 4 + r;
                const float v = acc[t][u][r];
                if (col < 150)      P1[(size_t)row * PPAD + col] = v;
                else if (col < 300) P2[(size_t)row * PPAD + (col - 150)] = v;
                else if (col < 450) AH1b[(size_t)row * K2 + (col - 300)] =
                                        f2bf(fmaxf(v + ab1[col - 300], 0.f));
                else if (col < 600) PE[(size_t)row * PPAD + (col - 450)] = v;
            }
        }
}

// ---------------------------------------------------------------------------
// attn_tail: one wave per block, 16 tokens, grid 256. A2pk packed frags.
// ---------------------------------------------------------------------------
__global__ __launch_bounds__(64) void attn_tail(
    const ushort* __restrict__ AH1b, const ushort* __restrict__ A2pk,
    const float* __restrict__ ab2, const float* __restrict__ aW3,
    const float* __restrict__ ab3, float* __restrict__ attns)
{
    const int tok0 = blockIdx.x * 16;
    const int lane = threadIdx.x;
    const int quad = lane >> 4, l16 = lane & 15;

    bfrag af[5];
#pragma unroll
    for (int ks = 0; ks < 5; ++ks)
        af[ks] = *(const bfrag*)(AH1b + (size_t)(tok0 + l16) * K2 + ks * 32 + quad * 8);

    float part[4] = {0.f, 0.f, 0.f, 0.f};
    for (int ct = 0; ct < 10; ++ct) {
        ffrag acc = (ffrag){0.f, 0.f, 0.f, 0.f};
#pragma unroll
        for (int ks = 0; ks < 5; ++ks) {
            const size_t tk = (size_t)ct * 5 + ks;
            const bfrag fh = *(const bfrag*)(A2pk + ((tk * 2 + 0) * 64 + lane) * 8);
            const bfrag fl = *(const bfrag*)(A2pk + ((tk * 2 + 1) * 64 + lane) * 8);
            acc = __builtin_amdgcn_mfma_f32_16x16x32_bf16(af[ks], fh, acc, 0, 0, 0);
            acc = __builtin_amdgcn_mfma_f32_16x16x32_bf16(af[ks], fl, acc, 0, 0, 0);
        }
        const int col = ct * 16 + l16;
        const float s2 = (col < HDIM) ? ab2[col] : 0.f;
        const float s3 = (col < HDIM) ? aW3[col] : 0.f;
#pragma unroll
        for (int r = 0; r < 4; ++r) part[r] += fmaxf(acc[r] + s2, 0.f) * s3;
    }

#pragma unroll
    for (int off = 1; off < 16; off <<= 1) {
#pragma unroll
        for (int r = 0; r < 4; ++r) part[r] += __shfl_xor(part[r], off, 64);
    }
    if (l16 == 0) {
        const float b3 = ab3[0];
#pragma unroll
        for (int r = 0; r < 4; ++r)
            attns[tok0 + quad * 4 + r] = part[r] + b3;
    }
}

// ---------------------------------------------------------------------------
// span: uniform-n blocks (blockIdx = nIdx*64 + mChunk). Phase 1: h1 fp32
// (float4, unrolled predicated PE prefetch) -> bf16 LDS. Phase 2: MFMA
// layer-2 with packed W2pk frags. Epilogue relu*sW3, shfl reduce.
// ---------------------------------------------------------------------------
#define RB2 64
__global__ __launch_bounds__(256) void span_kernel(
    const float* __restrict__ attns, const float* __restrict__ P1,
    const float* __restrict__ P2, const float* __restrict__ PE,
    const float* __restrict__ sb1, const ushort* __restrict__ W2pk,
    const float* __restrict__ sb2, const float* __restrict__ sW3,
    const float* __restrict__ sb3, float* __restrict__ out)
{
    const int nIdx = blockIdx.x >> 6, mChunk = blockIdx.x & 63;
    const int n = nIdx + 1;
    const int Mn = LTOK - n + 1;
    const int m0 = mChunk * 64;
    const int nrows = min(64, Mn - m0);
    const int offn = nIdx * LTOK - (nIdx * (nIdx - 1)) / 2;  // sum_{j<n}(L-j+1)

    const int tid = threadIdx.x;
    const int w = tid >> 6, lane = tid & 63, quad = lane >> 4, l16 = lane & 15;

    __shared__ __align__(16) ushort h1b[RB2 * K2];
    __shared__ float wgt[RB2][MAXN];

    if (tid < RB2) {
        const int m = min(m0 + tid, Mn - 1);
        float mx = -1e30f;
        for (int j = 0; j < n; ++j) mx = fmaxf(mx, attns[m + j]);
        float tp[MAXN]; float s = 0.f;
        for (int j = 0; j < n; ++j) { tp[j] = expf(attns[m + j] - mx); s += tp[j]; }
        const float inv = 1.f / s;
#pragma unroll
        for (int j = 0; j < MAXN; ++j) wgt[tid][j] = (j < n) ? tp[j] * inv : 0.f;
    }
    __syncthreads();

    // phase 1: h1 fp32 (float4) -> bf16 LDS; 10 independent PE loads per item
    for (int item = tid; item < RB2 * (K2 / 4); item += 256) {
        const int r = item / (K2 / 4), cq = item % (K2 / 4);
        const int c0 = cq * 4;
        const int m = min(m0 + r, Mn - 1);
        float4 a = {0.f, 0.f, 0.f, 0.f};
        if (c0 < HDIM) {
            const float4 p1 = *(const float4*)(P1 + (size_t)m * PPAD + c0);
            const float4 p2 = *(const float4*)(P2 + (size_t)(m + n - 1) * PPAD + c0);
            a.x = p1.x + p2.x; a.y = p1.y + p2.y;
            a.z = p1.z + p2.z; a.w = p1.w + p2.w;
#pragma unroll
            for (int j = 0; j < MAXN; ++j) {
                const int mj = min(m + j, LTOK - 1);        // clamped; wj=0 past n
                const float4 pe = *(const float4*)(PE + (size_t)mj * PPAD + c0);
                const float wj = wgt[r][j];
                a.x = fmaf(wj, pe.x, a.x); a.y = fmaf(wj, pe.y, a.y);
                a.z = fmaf(wj, pe.z, a.z); a.w = fmaf(wj, pe.w, a.w);
            }
        }
        ushort o[4];
        o[0] = (c0 + 0 < HDIM) ? f2bf(fmaxf(a.x + sb1[c0 + 0], 0.f)) : (ushort)0;
        o[1] = (c0 + 1 < HDIM) ? f2bf(fmaxf(a.y + sb1[c0 + 1], 0.f)) : (ushort)0;
        o[2] = (c0 + 2 < HDIM) ? f2bf(fmaxf(a.z + sb1[c0 + 2], 0.f)) : (ushort)0;
        o[3] = (c0 + 3 < HDIM) ? f2bf(fmaxf(a.w + sb1[c0 + 3], 0.f)) : (ushort)0;
        *(uint2*)&h1b[r * K2 + c0] = *(uint2*)o;
    }
    __syncthreads();

    // phase 2: wave w -> rows w*16..+15, all 10 col-tiles
    bfrag af[5];
#pragma unroll
    for (int ks = 0; ks < 5; ++ks)
        af[ks] = *(const bfrag*)&h1b[(w * 16 + l16) * K2 + ks * 32 + quad * 8];

    float part[4] = {0.f, 0.f, 0.f, 0.f};
    for (int ct = 0; ct < 10; ++ct) {
        ffrag acc = (ffrag){0.f, 0.f, 0.f, 0.f};
#pragma unroll
        for (int ks = 0; ks < 5; ++ks) {
            const size_t tk = (size_t)ct * 5 + ks;
            const bfrag fh = *(const bfrag*)(W2pk + ((tk * 2 + 0) * 64 + lane) * 8);
            const bfrag fl = *(const bfrag*)(W2pk + ((tk * 2 + 1) * 64 + lane) * 8);
            acc = __builtin_amdgcn_mfma_f32_16x16x32_bf16(af[ks], fh, acc, 0, 0, 0);
            acc = __builtin_amdgcn_mfma_f32_16x16x32_bf16(af[ks], fl, acc, 0, 0, 0);
        }
        const int col = ct * 16 + l16;
        const float s2 = (col < HDIM) ? sb2[col] : 0.f;
        const float s3 = (col < HDIM) ? sW3[col] : 0.f;
#pragma unroll
        for (int r = 0; r < 4; ++r) part[r] += fmaxf(acc[r] + s2, 0.f) * s3;
    }

#pragma unroll
    for (int off = 1; off < 16; off <<= 1) {
#pragma unroll
        for (int r = 0; r < 4; ++r) part[r] += __shfl_xor(part[r], off, 64);
    }
    if (l16 == 0) {
        const float b3 = sb3[0];
#pragma unroll
        for (int r = 0; r < 4; ++r) {
            const int lr = w * 16 + quad * 4 + r;
            if (lr < nrows) out[offn + m0 + lr] = part[r] + b3;
        }
    }
}

// ---------------------------------------------------------------------------
extern "C" void kernel_launch(void* const* d_in, const int* in_sizes, int n_in,
                              void* d_out, int out_size, void* d_ws, size_t ws_size,
                              hipStream_t stream) {
    const float* embeds = (const float*)d_in[0];
    const float* states = (const float*)d_in[1];
    const float* aW1 = (const float*)d_in[2];
    const float* ab1 = (const float*)d_in[3];
    const float* aW2 = (const float*)d_in[4];
    const float* ab2 = (const float*)d_in[5];
    const float* aW3 = (const float*)d_in[6];
    const float* ab3 = (const float*)d_in[7];
    const float* sW1 = (const float*)d_in[8];
    const float* sb1 = (const float*)d_in[9];
    const float* sW2 = (const float*)d_in[10];
    const float* sb2 = (const float*)d_in[11];
    const float* sW3 = (const float*)d_in[12];
    const float* sb3 = (const float*)d_in[13];
    float* out = (float*)d_out;

    // ws: fp32 attns | P1 | P2 | PE (PPAD rows), bf16 AH1b | Apk | Wpk |
    //     W2pk | A2pk   (~25.5 MB)
    float* attns = (float*)d_ws;
    float* P1 = attns + LTOK;
    float* P2 = P1 + (size_t)LTOK * PPAD;
    float* PE = P2 + (size_t)LTOK * PPAD;
    ushort* AH1b = (ushort*)(PE + (size_t)LTOK * PPAD);  // LTOK*K2
    ushort* Apk  = AH1b + (size_t)LTOK * K2;             // 786432*8
    ushort* Wpk  = Apk + (size_t)ITEMS_A * 8;            // 40*48*2*512
    ushort* W2pk = Wpk + (size_t)40 * NKT * 2 * 512;     // 50*2*512
    ushort* A2pk = W2pk + (size_t)50 * 2 * 512;

    prep_kernel<<<(ITEMS_TOT + 255) / 256, 256, 0, stream>>>(
        embeds, states, aW1, aW2, sW1, sW2, Apk, Wpk, W2pk, A2pk, AH1b);
    k_proj<<<640, 256, 0, stream>>>(
        Apk, Wpk, ab1, P1, P2, PE, AH1b);
    attn_tail<<<LTOK / 16, 64, 0, stream>>>(
        AH1b, A2pk, ab2, aW3, ab3, attns);
    span_kernel<<<640, 256, 0, stream>>>(
        attns, P1, P2, PE, sb1, W2pk, sb2, sW3, sb3, out);
}

// Round 8
// 159.574 us; speedup vs baseline: 1.5514x; 1.0983x over previous
//
#include <hip/hip_runtime.h>
#include <hip/hip_bf16.h>
#include <math.h>

#define LTOK 4096
#define EDIM 512
#define SDIM 1024
#define HDIM 150
#define PPAD 152           // padded row stride for P1/P2/PE (fp32)
#define MAXN 10
#define TOTAL_ROWS 40915   // sum_{n=1..10} (L - n + 1)
#define KA 1536            // padded K for token GEMM: 1024 states + 512 embeds
#define NC 640             // padded col count (600 real: P1|P2|AH1|PE)
#define K2 160             // padded K and N for 150x150 layers
#define NKT (KA / 32)      // 48 k-tiles

typedef _Float16 hfrag __attribute__((ext_vector_type(8)));  // 8 fp16, 4 VGPRs
typedef float ffrag __attribute__((ext_vector_type(4)));     // MFMA C/D

// Packed-fragment layouts (fp16, single precision — no hi/lo):
//   Apk [(g*48 + kt)*64 + lane][8]  : A[row=g*16+l16][k=kt*32+quad*8+j]
//   Wpk [(cg*48 + kt)*64 + lane][8] : W[col=cg*16+l16][k...]
//   W2pk/A2pk [(ct*5+ks)*64 + lane][8]
// A wave's frag load = base + lane*16B -> one contiguous 1 KB transaction.

#define ITEMS_A   (LTOK * (KA / 8))   // 786432  Apk
#define ITEMS_W   (NC * (KA / 8))     // 122880  Wpk
#define ITEMS_W2  (K2 * (K2 / 8))     // 3200    W2pk (sW2)
#define ITEMS_A2  (K2 * (K2 / 8))     // 3200    A2pk (aW2)
#define ITEMS_Z   (LTOK * K2 / 8)     // 81920   zero AH1h (incl. k-pad)
#define ITEMS_TOT (ITEMS_A + ITEMS_W + ITEMS_W2 + ITEMS_A2 + ITEMS_Z)

// ---------------------------------------------------------------------------
// prep: fp32 -> fp16 conversion + MFMA-fragment packing + AH1h zero.
// ---------------------------------------------------------------------------
__global__ __launch_bounds__(256) void prep_kernel(
    const float* __restrict__ embeds, const float* __restrict__ states,
    const float* __restrict__ aW1, const float* __restrict__ aW2,
    const float* __restrict__ sW1, const float* __restrict__ sW2,
    _Float16* __restrict__ Apk, _Float16* __restrict__ Wpk,
    _Float16* __restrict__ W2pk, _Float16* __restrict__ A2pk,
    _Float16* __restrict__ AH1h)
{
    int it = blockIdx.x * 256 + threadIdx.x;
    if (it < ITEMS_A) {
        const int rem = it % 3072;               // 48*64
        const int g = it / 3072, kt = rem >> 6, lane = rem & 63;
        const int row = g * 16 + (lane & 15);
        const int k0 = kt * 32 + (lane >> 4) * 8;
        const float* src = (k0 < SDIM) ? (states + (size_t)row * SDIM + k0)
                                       : (embeds + (size_t)row * EDIM + (k0 - SDIM));
        const float4 v0 = *(const float4*)src;
        const float4 v1 = *(const float4*)(src + 4);
        _Float16 o[8] = {(_Float16)v0.x, (_Float16)v0.y, (_Float16)v0.z, (_Float16)v0.w,
                         (_Float16)v1.x, (_Float16)v1.y, (_Float16)v1.z, (_Float16)v1.w};
        *(uint4*)(Apk + (size_t)it * 8) = *(uint4*)o;
        return;
    }
    it -= ITEMS_A;
    if (it < ITEMS_W) {
        const int rem = it % 3072;
        const int cg = it / 3072, kt = rem >> 6, lane = rem & 63;
        const int col = cg * 16 + (lane & 15);
        const int k0 = kt * 32 + (lane >> 4) * 8;
        const int g4 = (col < 600) ? (col / HDIM) : -1;
        const int cj = col % HDIM;
        _Float16 o[8];
        for (int j = 0; j < 8; ++j) {
            const int k = k0 + j;
            float wv = 0.f;
            if (g4 == 0 && k < SDIM) wv = sW1[(size_t)k * HDIM + cj];
            else if (g4 == 1 && k < SDIM) wv = sW1[(size_t)(SDIM + k) * HDIM + cj];
            else if (g4 == 2 && k < SDIM) wv = aW1[(size_t)k * HDIM + cj];
            else if (g4 == 3 && k >= SDIM) wv = sW1[(size_t)(SDIM + k) * HDIM + cj]; // rows 2048+(k-1024)
            o[j] = (_Float16)wv;
        }
        const size_t tk = (size_t)cg * 48 + kt;
        *(uint4*)(Wpk + (tk * 64 + lane) * 8) = *(uint4*)o;
        return;
    }
    it -= ITEMS_W;
    if (it < ITEMS_W2 + ITEMS_A2) {
        const bool is_a = (it >= ITEMS_W2);
        const int li = is_a ? (it - ITEMS_W2) : it;
        const float* src = is_a ? aW2 : sW2;
        _Float16* dst = is_a ? A2pk : W2pk;
        const int tk = li >> 6, lane = li & 63;          // tk = ct*5+ks (0..49)
        const int col = (tk / 5) * 16 + (lane & 15);
        const int k0 = (tk % 5) * 32 + (lane >> 4) * 8;
        _Float16 o[8];
        for (int j = 0; j < 8; ++j) {
            const int k = k0 + j;
            float wv = (col < HDIM && k < HDIM) ? src[(size_t)k * HDIM + col] : 0.f;
            o[j] = (_Float16)wv;
        }
        *(uint4*)(dst + ((size_t)tk * 64 + lane) * 8) = *(uint4*)o;
        return;
    }
    it -= ITEMS_W2 + ITEMS_A2;
    if (it < ITEMS_Z) {
        const uint4 z = {0u, 0u, 0u, 0u};
        *(uint4*)(AH1h + (size_t)it * 8) = z;
    }
}

// ---------------------------------------------------------------------------
// k_proj v5: C[4096 x 640] via mfma_f32_16x16x32_f16 — no LDS, no barriers,
// all loads contiguous packed-fragment streams. BM=64 x BN=64, grid 640,
// 4 waves (2x2), wave-tile 32x32: 2 A-frags + 2 B-frags + 4 MFMAs per kt.
// ---------------------------------------------------------------------------
__global__ __launch_bounds__(256) void k_proj(
    const _Float16* __restrict__ Apk, const _Float16* __restrict__ Wpk,
    const float* __restrict__ ab1,
    float* __restrict__ P1, float* __restrict__ P2,
    float* __restrict__ PE, _Float16* __restrict__ AH1h)
{
    const int bM = blockIdx.x & 63, bN = blockIdx.x >> 6;
    const int tid = threadIdx.x;
    const int w = tid >> 6, lane = tid & 63;
    const int quad = lane >> 4, l16 = lane & 15;
    const int wm = w & 1, wn = w >> 1;

    const int gbase = bM * 4 + wm * 2;      // two 16-row groups
    const int cgbase = bN * 4 + wn * 2;     // two 16-col groups

    ffrag acc[2][2];
#pragma unroll
    for (int t = 0; t < 2; ++t)
#pragma unroll
        for (int u = 0; u < 2; ++u) acc[t][u] = (ffrag){0.f, 0.f, 0.f, 0.f};

    const _Float16* a0p = Apk + ((size_t)(gbase + 0) * NKT) * 512 + lane * 8;
    const _Float16* a1p = Apk + ((size_t)(gbase + 1) * NKT) * 512 + lane * 8;
    const _Float16* b0p = Wpk + ((size_t)(cgbase + 0) * NKT) * 512 + lane * 8;
    const _Float16* b1p = Wpk + ((size_t)(cgbase + 1) * NKT) * 512 + lane * 8;

#pragma unroll 4
    for (int kt = 0; kt < NKT; ++kt) {
        const hfrag a0 = *(const hfrag*)(a0p + (size_t)kt * 512);
        const hfrag a1 = *(const hfrag*)(a1p + (size_t)kt * 512);
        const hfrag b0 = *(const hfrag*)(b0p + (size_t)kt * 512);
        const hfrag b1 = *(const hfrag*)(b1p + (size_t)kt * 512);
        acc[0][0] = __builtin_amdgcn_mfma_f32_16x16x32_f16(a0, b0, acc[0][0], 0, 0, 0);
        acc[1][0] = __builtin_amdgcn_mfma_f32_16x16x32_f16(a1, b0, acc[1][0], 0, 0, 0);
        acc[0][1] = __builtin_amdgcn_mfma_f32_16x16x32_f16(a0, b1, acc[0][1], 0, 0, 0);
        acc[1][1] = __builtin_amdgcn_mfma_f32_16x16x32_f16(a1, b1, acc[1][1], 0, 0, 0);
    }

#pragma unroll
    for (int t = 0; t < 2; ++t)
#pragma unroll
        for (int u = 0; u < 2; ++u) {
            const int col = (cgbase + u) * 16 + l16;
#pragma unroll
            for (int r = 0; r < 4; ++r) {
                const int row = (gbase + t) * 16 + quad * 4 + r;
                const float v = acc[t][u][r];
                if (col < 150)      P1[(size_t)row * PPAD + col] = v;
                else if (col < 300) P2[(size_t)row * PPAD + (col - 150)] = v;
                else if (col < 450) AH1h[(size_t)row * K2 + (col - 300)] =
                                        (_Float16)fmaxf(v + ab1[col - 300], 0.f);
                else if (col < 600) PE[(size_t)row * PPAD + (col - 450)] = v;
            }
        }
}

// ---------------------------------------------------------------------------
// attn_tail: one wave per block, 16 tokens, grid 256. A2pk packed frags.
// ---------------------------------------------------------------------------
__global__ __launch_bounds__(64) void attn_tail(
    const _Float16* __restrict__ AH1h, const _Float16* __restrict__ A2pk,
    const float* __restrict__ ab2, const float* __restrict__ aW3,
    const float* __restrict__ ab3, float* __restrict__ attns)
{
    const int tok0 = blockIdx.x * 16;
    const int lane = threadIdx.x;
    const int quad = lane >> 4, l16 = lane & 15;

    hfrag af[5];
#pragma unroll
    for (int ks = 0; ks < 5; ++ks)
        af[ks] = *(const hfrag*)(AH1h + (size_t)(tok0 + l16) * K2 + ks * 32 + quad * 8);

    float part[4] = {0.f, 0.f, 0.f, 0.f};
    for (int ct = 0; ct < 10; ++ct) {
        ffrag acc = (ffrag){0.f, 0.f, 0.f, 0.f};
#pragma unroll
        for (int ks = 0; ks < 5; ++ks) {
            const size_t tk = (size_t)ct * 5 + ks;
            const hfrag fb = *(const hfrag*)(A2pk + (tk * 64 + lane) * 8);
            acc = __builtin_amdgcn_mfma_f32_16x16x32_f16(af[ks], fb, acc, 0, 0, 0);
        }
        const int col = ct * 16 + l16;
        const float s2 = (col < HDIM) ? ab2[col] : 0.f;
        const float s3 = (col < HDIM) ? aW3[col] : 0.f;
#pragma unroll
        for (int r = 0; r < 4; ++r) part[r] += fmaxf(acc[r] + s2, 0.f) * s3;
    }

#pragma unroll
    for (int off = 1; off < 16; off <<= 1) {
#pragma unroll
        for (int r = 0; r < 4; ++r) part[r] += __shfl_xor(part[r], off, 64);
    }
    if (l16 == 0) {
        const float b3 = ab3[0];
#pragma unroll
        for (int r = 0; r < 4; ++r)
            attns[tok0 + quad * 4 + r] = part[r] + b3;
    }
}

// ---------------------------------------------------------------------------
// span: uniform-n blocks (blockIdx = nIdx*64 + mChunk). Phase 1: h1 fp32
// (float4, unrolled predicated PE prefetch) -> fp16 LDS. Phase 2: MFMA
// layer-2 with packed W2pk frags. Epilogue relu*sW3, shfl reduce.
// ---------------------------------------------------------------------------
#define RB2 64
__global__ __launch_bounds__(256) void span_kernel(
    const float* __restrict__ attns, const float* __restrict__ P1,
    const float* __restrict__ P2, const float* __restrict__ PE,
    const float* __restrict__ sb1, const _Float16* __restrict__ W2pk,
    const float* __restrict__ sb2, const float* __restrict__ sW3,
    const float* __restrict__ sb3, float* __restrict__ out)
{
    const int nIdx = blockIdx.x >> 6, mChunk = blockIdx.x & 63;
    const int n = nIdx + 1;
    const int Mn = LTOK - n + 1;
    const int m0 = mChunk * 64;
    const int nrows = min(64, Mn - m0);
    const int offn = nIdx * LTOK - (nIdx * (nIdx - 1)) / 2;  // sum_{j<n}(L-j+1)

    const int tid = threadIdx.x;
    const int w = tid >> 6, lane = tid & 63, quad = lane >> 4, l16 = lane & 15;

    __shared__ __align__(16) _Float16 h1h[RB2 * K2];
    __shared__ float wgt[RB2][MAXN];

    if (tid < RB2) {
        const int m = min(m0 + tid, Mn - 1);
        float mx = -1e30f;
        for (int j = 0; j < n; ++j) mx = fmaxf(mx, attns[m + j]);
        float tp[MAXN]; float s = 0.f;
        for (int j = 0; j < n; ++j) { tp[j] = expf(attns[m + j] - mx); s += tp[j]; }
        const float inv = 1.f / s;
#pragma unroll
        for (int j = 0; j < MAXN; ++j) wgt[tid][j] = (j < n) ? tp[j] * inv : 0.f;
    }
    __syncthreads();

    // phase 1: h1 fp32 (float4) -> fp16 LDS; 10 independent PE loads per item
    for (int item = tid; item < RB2 * (K2 / 4); item += 256) {
        const int r = item / (K2 / 4), cq = item % (K2 / 4);
        const int c0 = cq * 4;
        const int m = min(m0 + r, Mn - 1);
        float4 a = {0.f, 0.f, 0.f, 0.f};
        if (c0 < HDIM) {
            const float4 p1 = *(const float4*)(P1 + (size_t)m * PPAD + c0);
            const float4 p2 = *(const float4*)(P2 + (size_t)(m + n - 1) * PPAD + c0);
            a.x = p1.x + p2.x; a.y = p1.y + p2.y;
            a.z = p1.z + p2.z; a.w = p1.w + p2.w;
#pragma unroll
            for (int j = 0; j < MAXN; ++j) {
                const int mj = min(m + j, LTOK - 1);        // clamped; wj=0 past n
                const float4 pe = *(const float4*)(PE + (size_t)mj * PPAD + c0);
                const float wj = wgt[r][j];
                a.x = fmaf(wj, pe.x, a.x); a.y = fmaf(wj, pe.y, a.y);
                a.z = fmaf(wj, pe.z, a.z); a.w = fmaf(wj, pe.w, a.w);
            }
        }
        _Float16 o[4];
        o[0] = (c0 + 0 < HDIM) ? (_Float16)fmaxf(a.x + sb1[c0 + 0], 0.f) : (_Float16)0.f;
        o[1] = (c0 + 1 < HDIM) ? (_Float16)fmaxf(a.y + sb1[c0 + 1], 0.f) : (_Float16)0.f;
        o[2] = (c0 + 2 < HDIM) ? (_Float16)fmaxf(a.z + sb1[c0 + 2], 0.f) : (_Float16)0.f;
        o[3] = (c0 + 3 < HDIM) ? (_Float16)fmaxf(a.w + sb1[c0 + 3], 0.f) : (_Float16)0.f;
        *(uint2*)&h1h[r * K2 + c0] = *(uint2*)o;
    }
    __syncthreads();

    // phase 2: wave w -> rows w*16..+15, all 10 col-tiles
    hfrag af[5];
#pragma unroll
    for (int ks = 0; ks < 5; ++ks)
        af[ks] = *(const hfrag*)&h1h[(w * 16 + l16) * K2 + ks * 32 + quad * 8];

    float part[4] = {0.f, 0.f, 0.f, 0.f};
    for (int ct = 0; ct < 10; ++ct) {
        ffrag acc = (ffrag){0.f, 0.f, 0.f, 0.f};
#pragma unroll
        for (int ks = 0; ks < 5; ++ks) {
            const size_t tk = (size_t)ct * 5 + ks;
            const hfrag fb = *(const hfrag*)(W2pk + (tk * 64 + lane) * 8);
            acc = __builtin_amdgcn_mfma_f32_16x16x32_f16(af[ks], fb, acc, 0, 0, 0);
        }
        const int col = ct * 16 + l16;
        const float s2 = (col < HDIM) ? sb2[col] : 0.f;
        const float s3 = (col < HDIM) ? sW3[col] : 0.f;
#pragma unroll
        for (int r = 0; r < 4; ++r) part[r] += fmaxf(acc[r] + s2, 0.f) * s3;
    }

#pragma unroll
    for (int off = 1; off < 16; off <<= 1) {
#pragma unroll
        for (int r = 0; r < 4; ++r) part[r] += __shfl_xor(part[r], off, 64);
    }
    if (l16 == 0) {
        const float b3 = sb3[0];
#pragma unroll
        for (int r = 0; r < 4; ++r) {
            const int lr = w * 16 + quad * 4 + r;
            if (lr < nrows) out[offn + m0 + lr] = part[r] + b3;
        }
    }
}

// ---------------------------------------------------------------------------
extern "C" void kernel_launch(void* const* d_in, const int* in_sizes, int n_in,
                              void* d_out, int out_size, void* d_ws, size_t ws_size,
                              hipStream_t stream) {
    const float* embeds = (const float*)d_in[0];
    const float* states = (const float*)d_in[1];
    const float* aW1 = (const float*)d_in[2];
    const float* ab1 = (const float*)d_in[3];
    const float* aW2 = (const float*)d_in[4];
    const float* ab2 = (const float*)d_in[5];
    const float* aW3 = (const float*)d_in[6];
    const float* ab3 = (const float*)d_in[7];
    const float* sW1 = (const float*)d_in[8];
    const float* sb1 = (const float*)d_in[9];
    const float* sW2 = (const float*)d_in[10];
    const float* sb2 = (const float*)d_in[11];
    const float* sW3 = (const float*)d_in[12];
    const float* sb3 = (const float*)d_in[13];
    float* out = (float*)d_out;

    // ws: fp32 attns | P1 | P2 | PE (PPAD rows), fp16 AH1h | Apk | Wpk |
    //     W2pk | A2pk   (~23.5 MB)
    float* attns = (float*)d_ws;
    float* P1 = attns + LTOK;
    float* P2 = P1 + (size_t)LTOK * PPAD;
    float* PE = P2 + (size_t)LTOK * PPAD;
    _Float16* AH1h = (_Float16*)(PE + (size_t)LTOK * PPAD);  // LTOK*K2
    _Float16* Apk  = AH1h + (size_t)LTOK * K2;               // ITEMS_A*8
    _Float16* Wpk  = Apk + (size_t)ITEMS_A * 8;              // NC*KA
    _Float16* W2pk = Wpk + (size_t)NC * KA;                  // K2*K2 each
    _Float16* A2pk = W2pk + (size_t)K2 * K2;

    prep_kernel<<<(ITEMS_TOT + 255) / 256, 256, 0, stream>>>(
        embeds, states, aW1, aW2, sW1, sW2, Apk, Wpk, W2pk, A2pk, AH1h);
    k_proj<<<640, 256, 0, stream>>>(
        Apk, Wpk, ab1, P1, P2, PE, AH1h);
    attn_tail<<<LTOK / 16, 64, 0, stream>>>(
        AH1h, A2pk, ab2, aW3, ab3, attns);
    span_kernel<<<640, 256, 0, stream>>>(
        attns, P1, P2, PE, sb1, W2pk, sb2, sW3, sb3, out);
}